// Round 2
// baseline (573.820 us; speedup 1.0000x reference)
//
#include <hip/hip_runtime.h>
#include <hip/hip_bf16.h>
#include <stdint.h>

// Problem constants
#define HEADS 16
#define DH    64
#define NB    8
#define MQ    256     // latents per batch
#define MX    4096    // media tokens per batch
#define JD    4352    // MX + MQ
#define DIMV  1024

typedef __bf16 bf16;
typedef __bf16 bf16x8 __attribute__((ext_vector_type(8)));
typedef float  f32x4  __attribute__((ext_vector_type(4)));

// XOR swizzle of 16B chunks within a 64-col (8-chunk) LDS row: spreads the
// stride-128B row aliasing across all banks. Same formula on stage + read.
#define SWZ(r, c) (((c) ^ ((r) & 7)))

__device__ __forceinline__ void gl_lds16(const void* g, void* l) {
  __builtin_amdgcn_global_load_lds((const __attribute__((address_space(1))) void*)g,
                                   (__attribute__((address_space(3))) void*)l, 16, 0, 0);
}

// ---------------- LayerNorm (f32 in, bf16 out) -------------------------------
__global__ __launch_bounds__(256) void ln_kernel(
    const float* __restrict__ X, const float* __restrict__ gw, const float* __restrict__ bw,
    bf16* __restrict__ out_kv, bf16* __restrict__ out_ln, int is_lat)
{
  const int row = blockIdx.x;
  const int tid = threadIdx.x;
  const float4 v = ((const float4*)(X + (size_t)row * DIMV))[tid];
  float s  = v.x + v.y + v.z + v.w;
  float s2 = v.x*v.x + v.y*v.y + v.z*v.z + v.w*v.w;
#pragma unroll
  for (int m = 1; m < 64; m <<= 1) { s += __shfl_xor(s, m); s2 += __shfl_xor(s2, m); }
  __shared__ float red[8];
  const int wid = tid >> 6;
  if ((tid & 63) == 0) { red[wid*2] = s; red[wid*2+1] = s2; }
  __syncthreads();
  s  = red[0] + red[2] + red[4] + red[6];
  s2 = red[1] + red[3] + red[5] + red[7];
  const float mu  = s * (1.0f / DIMV);
  const float var = s2 * (1.0f / DIMV) - mu * mu;
  const float rst = rsqrtf(var + 1e-5f);
  const float4 g4 = ((const float4*)gw)[tid];
  const float4 b4 = ((const float4*)bw)[tid];
  union { bf16 h[4]; short4 s4; } u;
  u.h[0] = (bf16)((v.x - mu) * rst * g4.x + b4.x);
  u.h[1] = (bf16)((v.y - mu) * rst * g4.y + b4.y);
  u.h[2] = (bf16)((v.z - mu) * rst * g4.z + b4.z);
  u.h[3] = (bf16)((v.w - mu) * rst * g4.w + b4.w);
  size_t kvrow;
  if (is_lat) { int b = row >> 8;  int i = row & 255;  kvrow = (size_t)b * JD + MX + i; }
  else        { int b = row >> 12; int j = row & 4095; kvrow = (size_t)b * JD + j; }
  *(short4*)(out_kv + kvrow * DIMV + tid * 4) = u.s4;
  if (is_lat) *(short4*)(out_ln + (size_t)row * DIMV + tid * 4) = u.s4;
}

// ---------------- Weight transpose + f32->bf16: in[R][C] -> out[C][R] --------
__global__ __launch_bounds__(256) void transpose_w(
    const float* __restrict__ in, bf16* __restrict__ out, int R, int C)
{
  __shared__ float t[64][65];
  const int tilesC = C >> 6;
  const int tc = blockIdx.x % tilesC, tr = blockIdx.x / tilesC;
  const int r0 = tr << 6, c0 = tc << 6;
  const int lr = threadIdx.x >> 4;
  const int lc = (threadIdx.x & 15) << 2;
#pragma unroll
  for (int p = 0; p < 4; p++) {
    float4 v = *(const float4*)&in[(size_t)(r0 + lr + p*16) * C + c0 + lc];
    t[lr + p*16][lc    ] = v.x; t[lr + p*16][lc + 1] = v.y;
    t[lr + p*16][lc + 2] = v.z; t[lr + p*16][lc + 3] = v.w;
  }
  __syncthreads();
#pragma unroll
  for (int p = 0; p < 4; p++) {
    const int oc = lr + p*16;
    union { bf16 h[4]; short4 s4; } u;
    u.h[0] = (bf16)t[lc    ][oc]; u.h[1] = (bf16)t[lc + 1][oc];
    u.h[2] = (bf16)t[lc + 2][oc]; u.h[3] = (bf16)t[lc + 3][oc];
    *(short4*)&out[(size_t)(c0 + oc) * R + r0 + lc] = u.s4;
  }
}

// ---------------- mask dtype detect + build ---------------------------------
__global__ __launch_bounds__(256) void mask_detect(
    const unsigned char* __restrict__ m, int n, int* __restrict__ flag)
{
  const int tid = threadIdx.x;
  int cnt = 0;
  for (int i = tid; i < n; i += 256) cnt += (m[i] != 0) ? 1 : 0;
#pragma unroll
  for (int mm = 1; mm < 64; mm <<= 1) cnt += __shfl_xor(cnt, mm);
  __shared__ int r4[4];
  if ((tid & 63) == 0) r4[tid >> 6] = cnt;
  __syncthreads();
  if (tid == 0) {
    int t = r4[0] + r4[1] + r4[2] + r4[3];
    flag[0] = (t * 16 > n * 5) ? 1 : 0;   // frac > 0.3125 -> byte mode
  }
}

__global__ __launch_bounds__(256) void mask_build(
    const void* __restrict__ mraw, const int* __restrict__ flag, float* __restrict__ mm)
{
  const int idx = blockIdx.x * 256 + threadIdx.x;   // < 34816
  const int b = idx / JD, j = idx - b * JD;
  float v = 1.0f;
  if (j < MX) {
    bool masked = (*flag) ? (((const unsigned char*)mraw)[b * MX + j] != 0)
                          : (((const int*)mraw)[b * MX + j] != 0);
    v = masked ? 0.0f : 1.0f;
  }
  mm[idx] = v;
}

// ---------------- GEMM: 256x256 tile, BK=64, 2-phase counted-vmcnt pipeline --
// 512 threads = 8 waves (2 M-waves x 4 N-waves), per-wave output 128x64.
// LDS 128 KiB: A[2][256][64] + B[2][256][64] bf16, double buffered.
// Schedule per K-tile t (buf c = t&1), 32-MFMA clusters, 5 barriers/tile:
//   phase0: ds_read afrag(m0..3)+bfrag(all); bar; MFMA x32; bar
//           (B region of buf c now free)
//   phase1: ds_read afrag(m4..7); issue stageB(t+2 -> buf c); bar; MFMA x32; bar
//           (A region of buf c now free)
//   bound : issue stageA(t+2 -> buf c); s_waitcnt vmcnt(8)  [tile t+1 landed,
//           tile t+2's 8 loads stay in flight]; bar
// Prefetch distance ~1 full tile (~2.5k cyc) for every load -> cold waits.
// bx <  kSplitX : rows-mode -> outR[(m0+row)*1024 + n0 + col] (bf16)
// bx >= kSplitX : V-mode    -> operands SWAPPED; store outVT[bh][dd][j].
__global__ __launch_bounds__(512, 2) void gemm256(
    const bf16* __restrict__ A, const bf16* __restrict__ Bt,
    bf16* __restrict__ outR, bf16* __restrict__ outVT,
    int K, int kSplitX)
{
  __shared__ bf16 sm[65536];                 // 128 KiB: A0 A1 B0 B1, 32 KiB each

  const int tid = threadIdx.x;
  const int lane = tid & 63, wid = tid >> 6;
  const int wr = wid >> 2, wc = wid & 3;     // 2 x 4 wave grid
  const int lc = lane & 15, lq = lane >> 4;
  const int srow = tid >> 3, sc = tid & 7;
  const int ssw = SWZ(srow, sc) * 8;

  // XCD-bijective swizzle (nwg % 8 == 0): each XCD owns a contiguous m-range,
  // sweeping n-tiles fastest -> A-panel reuse in its private L2.
  int bid = blockIdx.y * gridDim.x + blockIdx.x;
  const int nwg = gridDim.x * gridDim.y;
  bid = (bid & 7) * (nwg >> 3) + (bid >> 3);
  const int bx = bid % gridDim.x;
  const int by = bid / gridDim.x;

  const bool vmode = (bx >= kSplitX);
  const int n0 = vmode ? 1024 + (bx - kSplitX) * 256 : bx * 256;
  const int m0 = by * 256;

  const bf16* Arow = vmode ? (Bt + (size_t)n0 * K) : (A + (size_t)m0 * K);
  const bf16* Brow = vmode ? (A + (size_t)m0 * K) : (Bt + (size_t)n0 * K);
  const bf16* Abase = Arow + (size_t)srow * K + ssw;
  const bf16* Bbase = Brow + (size_t)srow * K + ssw;

  // stage full A / B tile (4 x global_load_lds per thread each)
  auto stageA = [&](int cbuf, int kt) {
#pragma unroll
    for (int h = 0; h < 4; ++h)
      gl_lds16(Abase + (size_t)(h*64) * K + (size_t)kt * 64,
               &sm[cbuf*16384 + (h*64)*64 + tid*8]);
  };
  auto stageB = [&](int cbuf, int kt) {
#pragma unroll
    for (int h = 0; h < 4; ++h)
      gl_lds16(Bbase + (size_t)(h*64) * K + (size_t)kt * 64,
               &sm[32768 + cbuf*16384 + (h*64)*64 + tid*8]);
  };

  f32x4 acc[8][4];
#pragma unroll
  for (int i = 0; i < 8; i++)
#pragma unroll
    for (int j = 0; j < 4; j++)
#pragma unroll
      for (int r = 0; r < 4; r++) acc[i][j][r] = 0.f;

  const int NT = K >> 6;                     // 16 for K=1024 (NT >= 2 assumed)

  // Prologue: tiles 0 and 1 fully staged; wait leaves tile1's 8 loads in flight.
  stageB(0, 0); stageA(0, 0);
  stageB(1, 1); stageA(1, 1);
  asm volatile("s_waitcnt vmcnt(8)" ::: "memory");
  __builtin_amdgcn_s_barrier();

  for (int kt = 0; kt < NT; ++kt) {
    const int c = kt & 1;
    const bf16* As = sm + c * 16384;
    const bf16* Bs = sm + 32768 + c * 16384;
    const bool st = (kt + 2 < NT);

    // ---- phase 0: m-frags 0..3, all B frags ----
    bf16x8 bfrag[4][2];
    bf16x8 af0[4][2];
#pragma unroll
    for (int mi = 0; mi < 4; ++mi)
#pragma unroll
      for (int kk = 0; kk < 2; ++kk)
        af0[mi][kk] = *(const bf16x8*)&As[(wr*128 + mi*16 + lc)*64 + SWZ(lc, kk*4 + lq)*8];
#pragma unroll
    for (int n = 0; n < 4; ++n)
#pragma unroll
      for (int kk = 0; kk < 2; ++kk)
        bfrag[n][kk] = *(const bf16x8*)&Bs[(wc*64 + n*16 + lc)*64 + SWZ(lc, kk*4 + lq)*8];
    __builtin_amdgcn_s_barrier();
    __builtin_amdgcn_s_setprio(1);
#pragma unroll
    for (int kk = 0; kk < 2; ++kk)
#pragma unroll
      for (int mi = 0; mi < 4; ++mi)
#pragma unroll
        for (int n = 0; n < 4; ++n)
          acc[mi][n] = __builtin_amdgcn_mfma_f32_16x16x32_bf16(
              af0[mi][kk], bfrag[n][kk], acc[mi][n], 0, 0, 0);
    __builtin_amdgcn_s_setprio(0);
    __builtin_amdgcn_s_barrier();            // B region of buf c free

    // ---- phase 1: m-frags 4..7; prefetch B(t+2) into buf c ----
    bf16x8 af1[4][2];
#pragma unroll
    for (int mi = 0; mi < 4; ++mi)
#pragma unroll
      for (int kk = 0; kk < 2; ++kk)
        af1[mi][kk] = *(const bf16x8*)&As[(wr*128 + (mi+4)*16 + lc)*64 + SWZ(lc, kk*4 + lq)*8];
    if (st) stageB(c, kt + 2);
    __builtin_amdgcn_s_barrier();
    __builtin_amdgcn_s_setprio(1);
#pragma unroll
    for (int kk = 0; kk < 2; ++kk)
#pragma unroll
      for (int mi = 0; mi < 4; ++mi)
#pragma unroll
        for (int n = 0; n < 4; ++n)
          acc[mi+4][n] = __builtin_amdgcn_mfma_f32_16x16x32_bf16(
              af1[mi][kk], bfrag[n][kk], acc[mi+4][n], 0, 0, 0);
    __builtin_amdgcn_s_setprio(0);
    __builtin_amdgcn_s_barrier();            // A region of buf c free

    // ---- tile boundary: prefetch A(t+2); counted wait for tile t+1 ----
    if (kt + 1 < NT) {
      if (st) {
        stageA(c, kt + 2);
        asm volatile("s_waitcnt vmcnt(8)" ::: "memory");
      } else {
        asm volatile("s_waitcnt vmcnt(0)" ::: "memory");
      }
      __builtin_amdgcn_s_barrier();
    }
  }

  // ---- Epilogue: acc -> bf16 Ct[256][256] in LDS (32-chunk swizzle), then
  //      coalesced 16B row-major stores.
  __syncthreads();
  bf16* Ct = sm;
#pragma unroll
  for (int m = 0; m < 8; ++m)
#pragma unroll
    for (int n = 0; n < 4; ++n) {
      const int col = wc*64 + n*16 + lc;
      const int cch = col >> 3, cw = col & 7;
#pragma unroll
      for (int r = 0; r < 4; ++r) {
        const int row = wr*128 + m*16 + lq*4 + r;
        Ct[row*256 + (((cch ^ (row & 31)) << 3) + cw)] = (bf16)acc[m][n][r];
      }
    }
  __syncthreads();

  const int cch = tid & 31, r0 = tid >> 5;
  if (!vmode) {
#pragma unroll
    for (int i = 0; i < 16; ++i) {
      const int row = r0 + i*16;
      bf16x8 v = *(const bf16x8*)&Ct[row*256 + ((cch ^ (row & 31)) << 3)];
      *(bf16x8*)(outR + (size_t)(m0 + row) * 1024 + n0 + cch*8) = v;
    }
  } else {
    const int bb = m0 / JD;                // 256-row m-tiles never cross batches (JD = 17*256)
    const int jbase = m0 - bb * JD;
#pragma unroll
    for (int i = 0; i < 16; ++i) {
      const int row = r0 + i*16;
      const int cc = n0 + row - 1024;      // weight col in V half
      bf16x8 v = *(const bf16x8*)&Ct[row*256 + ((cch ^ (row & 31)) << 3)];
      bf16* dst = outVT + (((size_t)(bb*HEADS + (cc >> 6)))*64 + (cc & 63)) * JD
                        + jbase + cch*8;
      *(bf16x8*)dst = v;
    }
  }
}

// ---------------- GEMM: 128x128 tile, BK=64, swizzled LDS (small GEMMs) -----
// mode 0: Cf[row][n0+col] f32 direct (final projection).
// mode 1: rows-mode -> outR[(m0+row)*1024 + n0 + col] (bf16)
__global__ __launch_bounds__(256) void gemm128(
    const bf16* __restrict__ A, const bf16* __restrict__ Bt,
    float* __restrict__ Cf, bf16* __restrict__ outR, bf16* __restrict__ outVT,
    int N, int K, int kSplitX, int mode)
{
  __shared__ bf16 smem[2 * 128 * 64];
  bf16* As = smem;
  bf16* Bs = smem + 128 * 64;
  bf16* Ct = smem;                       // epilogue alias (128x128 bf16 = 32 KB)

  const int tid = threadIdx.x;
  const int lane = tid & 63, wid = tid >> 6;
  const int wr = wid >> 1, wc = wid & 1;
  const int bx = blockIdx.x;
  const int m0 = blockIdx.y * 128;
  const bool vmode = (mode == 1) && (bx >= kSplitX);
  const int n0 = vmode ? 1024 + (bx - kSplitX) * 128 : bx * 128;
  const int srow = tid >> 3, sc = tid & 7;
  const int ssw = SWZ(srow, sc) * 8;     // swizzled source chunk (elements)
  const int lc = lane & 15, lq = lane >> 4;

  f32x4 acc[4][4];
#pragma unroll
  for (int i = 0; i < 4; i++)
#pragma unroll
    for (int j = 0; j < 4; j++)
#pragma unroll
      for (int r = 0; r < 4; r++) acc[i][j][r] = 0.f;

  const bf16* Arow = vmode ? (Bt + (size_t)n0 * K) : (A + (size_t)m0 * K);
  const bf16* Brow = vmode ? (A + (size_t)m0 * K) : (Bt + (size_t)n0 * K);
  const bf16* Abase = Arow + (size_t)srow * K + ssw;
  const bf16* Bbase = Brow + (size_t)srow * K + ssw;

  for (int k0 = 0; k0 < K; k0 += 64) {
    __syncthreads();
#pragma unroll
    for (int q = 0; q < 4; q++) {
      gl_lds16(Abase + (size_t)q * 32 * K + k0, &As[(srow + q*32) * 64 + sc*8]);
      gl_lds16(Bbase + (size_t)q * 32 * K + k0, &Bs[(srow + q*32) * 64 + sc*8]);
    }
    asm volatile("s_waitcnt vmcnt(0)" ::: "memory");
    __syncthreads();
#pragma unroll
    for (int kk = 0; kk < 2; kk++) {
      bf16x8 af[4], bfr[4];
#pragma unroll
      for (int mi = 0; mi < 4; mi++)
        af[mi] = *(const bf16x8*)&As[(wr*64 + mi*16 + lc) * 64 + SWZ(lc, kk*4 + lq)*8];
#pragma unroll
      for (int ni = 0; ni < 4; ni++)
        bfr[ni] = *(const bf16x8*)&Bs[(wc*64 + ni*16 + lc) * 64 + SWZ(lc, kk*4 + lq)*8];
#pragma unroll
      for (int mi = 0; mi < 4; mi++)
#pragma unroll
        for (int ni = 0; ni < 4; ni++)
          acc[mi][ni] = __builtin_amdgcn_mfma_f32_16x16x32_bf16(af[mi], bfr[ni], acc[mi][ni], 0, 0, 0);
    }
  }

  if (mode == 0) {
#pragma unroll
    for (int mi = 0; mi < 4; mi++)
#pragma unroll
      for (int ni = 0; ni < 4; ni++) {
        const int r = m0 + wr*64 + mi*16 + lq*4;
        const int c = n0 + wc*64 + ni*16 + lc;
#pragma unroll
        for (int reg = 0; reg < 4; reg++)
          Cf[(size_t)(r + reg) * N + c] = acc[mi][ni][reg];
      }
    return;
  }

  // ---- LDS round-trip epilogue: acc -> bf16 Ct[128][128] (16-chunk swizzle),
  //      then coalesced 16B row-major stores.
  __syncthreads();
#pragma unroll
  for (int mi = 0; mi < 4; mi++)
#pragma unroll
    for (int ni = 0; ni < 4; ni++) {
      const int col = wc*64 + ni*16 + lc;
      const int cch = col >> 3, cw = col & 7;
#pragma unroll
      for (int reg = 0; reg < 4; reg++) {
        const int row = wr*64 + mi*16 + lq*4 + reg;
        Ct[row*128 + ((cch ^ (row & 15)) << 3) + cw] = (bf16)acc[mi][ni][reg];
      }
    }
  __syncthreads();

  const int cch = tid & 15, r0 = tid >> 4;
  {
    bf16* dst0 = outR + (size_t)m0 * 1024 + n0 + cch*8;
#pragma unroll
    for (int i = 0; i < 8; i++) {
      const int row = r0 + i*16;
      bf16x8 v = *(const bf16x8*)&Ct[row*128 + ((cch ^ r0) << 3)];
      *(bf16x8*)(dst0 + (size_t)row * 1024) = v;
    }
  }
}

// ---------------- Attention --------------------------------------------------
// 256 blocks = (b,h) x 2 q-tiles of 128; 512 threads (8 waves, 16 q-rows each).
// K and Q are consumed in natural GEMM layout (per-lane strided global addrs
// into linear LDS); V^T was materialized by the swapped-operand GEMM blocks.
__global__ __launch_bounds__(512) void attn_kernel(
    const bf16* __restrict__ Qrows,  // [2048][1024]
    const bf16* __restrict__ Krows,  // [B*JD][1024]
    const bf16* __restrict__ VT,     // [B][H][64][JD]
    const float* __restrict__ mmul,  // [B][JD]
    bf16* __restrict__ outp)         // [2048][1024]
{
  const int bh = blockIdx.x >> 1, qt = blockIdx.x & 1;
  const int b = bh >> 4, h = bh & 15;
  __shared__ bf16 Qs[128 * 64];
  __shared__ bf16 Ks[64 * 64];
  __shared__ bf16 VTs[64 * 64];
  __shared__ bf16 Ps[8][16 * 64];
  const int tid = threadIdx.x, lane = tid & 63, w = tid >> 6;
  const int lc = lane & 15, lq = lane >> 4;
  const int srow = tid >> 3, sc = tid & 7;
  const int ssw = SWZ(srow, sc) * 8;

  const bf16* Qg = Qrows + ((size_t)(b*MQ + qt*128)) * 1024 + h*64;
  const bf16* Kg = Krows + ((size_t)b * JD) * 1024 + h*64;
  const bf16* Vg = VT + ((size_t)bh * 64) * JD;

  gl_lds16(Qg + (size_t)srow * 1024 + ssw, &Qs[tid*8]);
  gl_lds16(Qg + (size_t)(srow + 64) * 1024 + ssw, &Qs[(tid + 512)*8]);
  asm volatile("s_waitcnt vmcnt(0)" ::: "memory");
  __syncthreads();

  bf16x8 qf[2];
#pragma unroll
  for (int kk = 0; kk < 2; kk++)
    qf[kk] = *(const bf16x8*)&Qs[(w*16 + lc) * 64 + SWZ(lc, kk*4 + lq)*8];

  f32x4 oacc[4];
  float den[4];
#pragma unroll
  for (int di = 0; di < 4; di++)
#pragma unroll
    for (int r = 0; r < 4; r++) oacc[di][r] = 0.f;
#pragma unroll
  for (int r = 0; r < 4; r++) den[r] = 0.f;

  for (int j0 = 0; j0 < JD; j0 += 64) {
    __syncthreads();
    gl_lds16(Kg + (size_t)(j0 + srow) * 1024 + ssw, &Ks[tid*8]);
    gl_lds16(Vg + (size_t)srow * JD + j0 + ssw, &VTs[tid*8]);
    asm volatile("s_waitcnt vmcnt(0)" ::: "memory");
    __syncthreads();

    // S = Q K^T
    f32x4 sacc[4];
#pragma unroll
    for (int nj = 0; nj < 4; nj++)
#pragma unroll
      for (int r = 0; r < 4; r++) sacc[nj][r] = 0.f;
#pragma unroll
    for (int kk = 0; kk < 2; kk++) {
      bf16x8 kf[4];
#pragma unroll
      for (int nj = 0; nj < 4; nj++)
        kf[nj] = *(const bf16x8*)&Ks[(nj*16 + lc) * 64 + SWZ(lc, kk*4 + lq)*8];
#pragma unroll
      for (int nj = 0; nj < 4; nj++)
        sacc[nj] = __builtin_amdgcn_mfma_f32_16x16x32_bf16(qf[kk], kf[nj], sacc[nj], 0, 0, 0);
    }

    // P = exp(S*scale) * mask ; partial denominators ; stage P for PV
#pragma unroll
    for (int nj = 0; nj < 4; nj++) {
      const float mm = mmul[b * JD + j0 + nj*16 + lc];
#pragma unroll
      for (int r = 0; r < 4; r++) {
        // scale * log2(e) = 0.125 * 1.4426950 = 0.18033688
        const float p = exp2f(sacc[nj][r] * 0.18033688f) * mm;
        den[r] += p;
        const int row = lq*4 + r, col = nj*16 + lc;
        Ps[w][row*64 + (((col >> 3) ^ (row & 7)) << 3) + (col & 7)] = (bf16)p;
      }
    }

    // O += P V
#pragma unroll
    for (int kk = 0; kk < 2; kk++) {
      bf16x8 pf = *(const bf16x8*)&Ps[w][lc*64 + SWZ(lc, kk*4 + lq)*8];
#pragma unroll
      for (int di = 0; di < 4; di++) {
        bf16x8 vf = *(const bf16x8*)&VTs[(di*16 + lc) * 64 + SWZ(lc, kk*4 + lq)*8];
        oacc[di] = __builtin_amdgcn_mfma_f32_16x16x32_bf16(pf, vf, oacc[di], 0, 0, 0);
      }
    }
  }

#pragma unroll
  for (int r = 0; r < 4; r++) {
    float d = den[r];
    d += __shfl_xor(d, 1); d += __shfl_xor(d, 2);
    d += __shfl_xor(d, 4); d += __shfl_xor(d, 8);
    den[r] = 1.0f / d;
  }

#pragma unroll
  for (int di = 0; di < 4; di++) {
    const int col = h*64 + di*16 + lc;
#pragma unroll
    for (int r = 0; r < 4; r++) {
      const int i = qt*128 + w*16 + lq*4 + r;
      outp[(size_t)(b*MQ + i) * 1024 + col] = (bf16)(oacc[di][r] * den[r]);
    }
  }
}

// ---------------- launch -----------------------------------------------------
extern "C" void kernel_launch(void* const* d_in, const int* in_sizes, int n_in,
                              void* d_out, int out_size, void* d_ws, size_t ws_size,
                              hipStream_t stream)
{
  const float* x    = (const float*)d_in[0];
  const float* lat  = (const float*)d_in[1];
  const void*  mraw = d_in[2];
  const float* nm_g = (const float*)d_in[3];
  const float* nm_b = (const float*)d_in[4];
  const float* nl_g = (const float*)d_in[5];
  const float* nl_b = (const float*)d_in[6];
  const float* Wq   = (const float*)d_in[7];
  const float* Wkv  = (const float*)d_in[8];
  const float* Wo   = (const float*)d_in[9];
  float* out = (float*)d_out;

  char* p = (char*)d_ws;
  auto alloc = [&](size_t bytes) { char* r = p; p += (bytes + 255) & ~(size_t)255; return r; };

  bf16*  kv_in  = (bf16*)alloc((size_t)NB * JD * DIMV * 2);          // 71.3 MB
  bf16*  Krows  = (bf16*)alloc((size_t)NB * JD * 1024 * 2);          // 71.3 MB
  bf16*  VTbuf  = (bf16*)alloc((size_t)NB * HEADS * 64 * JD * 2);    // 71.3 MB
  bf16*  WqT    = (bf16*)alloc((size_t)1024 * 1024 * 2);
  bf16*  WkvT   = (bf16*)alloc((size_t)2048 * 1024 * 2);
  bf16*  WoT    = (bf16*)alloc((size_t)1024 * 1024 * 2);
  bf16*  ln_buf = (bf16*)alloc((size_t)NB * MQ * DIMV * 2);
  bf16*  Qrows  = (bf16*)alloc((size_t)NB * MQ * 1024 * 2);
  bf16*  attout = (bf16*)alloc((size_t)NB * MQ * DIMV * 2);
  float* mmulp  = (float*)alloc((size_t)NB * JD * 4);
  int*   flag   = (int*)alloc(256);
  (void)ws_size; (void)in_sizes; (void)n_in; (void)out_size;

  ln_kernel<<<NB * MX, 256, 0, stream>>>(x,   nm_g, nm_b, kv_in, nullptr, 0);
  ln_kernel<<<NB * MQ, 256, 0, stream>>>(lat, nl_g, nl_b, kv_in, ln_buf, 1);
  transpose_w<<<256, 256, 0, stream>>>(Wq,  WqT,  1024, 1024);
  transpose_w<<<512, 256, 0, stream>>>(Wkv, WkvT, 1024, 2048);
  transpose_w<<<256, 256, 0, stream>>>(Wo,  WoT,  1024, 1024);
  mask_detect<<<1, 256, 0, stream>>>((const unsigned char*)mraw, 32768, flag);
  mask_build<<<136, 256, 0, stream>>>(mraw, flag, mmulp);

  // kv = kv_in @ Wkv : x<4 -> K rows (natural layout); x>=4 -> V^T (swapped ops)
  // 256^2 tiles: M = 8*JD = 34816 = 136 tiles (JD = 17*256, no batch crossing)
  gemm256<<<dim3(8, 136), 512, 0, stream>>>(kv_in, WkvT, Krows, VTbuf, 1024, 4);
  // q = ln @ Wq -> natural rows [2048][1024]
  gemm128<<<dim3(8, 16), 256, 0, stream>>>(ln_buf, WqT, nullptr, Qrows, nullptr,
                                           1024, 1024, 8, 1);
  attn_kernel<<<256, 512, 0, stream>>>(Qrows, Krows, VTbuf, mmulp, attout);
  // out = attout @ Wo -> f32 d_out
  gemm128<<<dim3(8, 16), 256, 0, stream>>>(attout, WoT, out, nullptr, nullptr,
                                           1024, 1024, 8, 0);
}

// Round 3
// 533.513 us; speedup vs baseline: 1.0756x; 1.0756x over previous
//
#include <hip/hip_runtime.h>
#include <hip/hip_bf16.h>
#include <stdint.h>

// Problem constants
#define HEADS 16
#define DH    64
#define NB    8
#define MQ    256     // latents per batch
#define MX    4096    // media tokens per batch
#define JD    4352    // MX + MQ
#define DIMV  1024
#define GK    1024    // K dim of every GEMM in this problem (compile-time)

typedef __bf16 bf16;
typedef __bf16 bf16x8 __attribute__((ext_vector_type(8)));
typedef float  f32x4  __attribute__((ext_vector_type(4)));

// XOR swizzle of 16B chunks within a 64-col (8-chunk) LDS row: spreads the
// stride-128B row aliasing across all banks. Same formula on stage + read.
#define SWZ(r, c) (((c) ^ ((r) & 7)))

#define VMW(n) asm volatile("s_waitcnt vmcnt(" #n ")" ::: "memory")

__device__ __forceinline__ void gl_lds16(const void* g, void* l) {
  __builtin_amdgcn_global_load_lds((const __attribute__((address_space(1))) void*)g,
                                   (__attribute__((address_space(3))) void*)l, 16, 0, 0);
}

// ---------------- LayerNorm (f32 in, bf16 out) -------------------------------
__global__ __launch_bounds__(256) void ln_kernel(
    const float* __restrict__ X, const float* __restrict__ gw, const float* __restrict__ bw,
    bf16* __restrict__ out_kv, bf16* __restrict__ out_ln, int is_lat)
{
  const int row = blockIdx.x;
  const int tid = threadIdx.x;
  const float4 v = ((const float4*)(X + (size_t)row * DIMV))[tid];
  float s  = v.x + v.y + v.z + v.w;
  float s2 = v.x*v.x + v.y*v.y + v.z*v.z + v.w*v.w;
#pragma unroll
  for (int m = 1; m < 64; m <<= 1) { s += __shfl_xor(s, m); s2 += __shfl_xor(s2, m); }
  __shared__ float red[8];
  const int wid = tid >> 6;
  if ((tid & 63) == 0) { red[wid*2] = s; red[wid*2+1] = s2; }
  __syncthreads();
  s  = red[0] + red[2] + red[4] + red[6];
  s2 = red[1] + red[3] + red[5] + red[7];
  const float mu  = s * (1.0f / DIMV);
  const float var = s2 * (1.0f / DIMV) - mu * mu;
  const float rst = rsqrtf(var + 1e-5f);
  const float4 g4 = ((const float4*)gw)[tid];
  const float4 b4 = ((const float4*)bw)[tid];
  union { bf16 h[4]; short4 s4; } u;
  u.h[0] = (bf16)((v.x - mu) * rst * g4.x + b4.x);
  u.h[1] = (bf16)((v.y - mu) * rst * g4.y + b4.y);
  u.h[2] = (bf16)((v.z - mu) * rst * g4.z + b4.z);
  u.h[3] = (bf16)((v.w - mu) * rst * g4.w + b4.w);
  size_t kvrow;
  if (is_lat) { int b = row >> 8;  int i = row & 255;  kvrow = (size_t)b * JD + MX + i; }
  else        { int b = row >> 12; int j = row & 4095; kvrow = (size_t)b * JD + j; }
  *(short4*)(out_kv + kvrow * DIMV + tid * 4) = u.s4;
  if (is_lat) *(short4*)(out_ln + (size_t)row * DIMV + tid * 4) = u.s4;
}

// ---------------- Weight transpose + f32->bf16: in[R][C] -> out[C][R] --------
__global__ __launch_bounds__(256) void transpose_w(
    const float* __restrict__ in, bf16* __restrict__ out, int R, int C)
{
  __shared__ float t[64][65];
  const int tilesC = C >> 6;
  const int tc = blockIdx.x % tilesC, tr = blockIdx.x / tilesC;
  const int r0 = tr << 6, c0 = tc << 6;
  const int lr = threadIdx.x >> 4;
  const int lc = (threadIdx.x & 15) << 2;
#pragma unroll
  for (int p = 0; p < 4; p++) {
    float4 v = *(const float4*)&in[(size_t)(r0 + lr + p*16) * C + c0 + lc];
    t[lr + p*16][lc    ] = v.x; t[lr + p*16][lc + 1] = v.y;
    t[lr + p*16][lc + 2] = v.z; t[lr + p*16][lc + 3] = v.w;
  }
  __syncthreads();
#pragma unroll
  for (int p = 0; p < 4; p++) {
    const int oc = lr + p*16;
    union { bf16 h[4]; short4 s4; } u;
    u.h[0] = (bf16)t[lc    ][oc]; u.h[1] = (bf16)t[lc + 1][oc];
    u.h[2] = (bf16)t[lc + 2][oc]; u.h[3] = (bf16)t[lc + 3][oc];
    *(short4*)&out[(size_t)(c0 + oc) * R + r0 + lc] = u.s4;
  }
}

// ---------------- mask dtype detect + build ---------------------------------
__global__ __launch_bounds__(256) void mask_detect(
    const unsigned char* __restrict__ m, int n, int* __restrict__ flag)
{
  const int tid = threadIdx.x;
  int cnt = 0;
  for (int i = tid; i < n; i += 256) cnt += (m[i] != 0) ? 1 : 0;
#pragma unroll
  for (int mm = 1; mm < 64; mm <<= 1) cnt += __shfl_xor(cnt, mm);
  __shared__ int r4[4];
  if ((tid & 63) == 0) r4[tid >> 6] = cnt;
  __syncthreads();
  if (tid == 0) {
    int t = r4[0] + r4[1] + r4[2] + r4[3];
    flag[0] = (t * 16 > n * 5) ? 1 : 0;   // frac > 0.3125 -> byte mode
  }
}

__global__ __launch_bounds__(256) void mask_build(
    const void* __restrict__ mraw, const int* __restrict__ flag, float* __restrict__ mm)
{
  const int idx = blockIdx.x * 256 + threadIdx.x;   // < 34816
  const int b = idx / JD, j = idx - b * JD;
  float v = 1.0f;
  if (j < MX) {
    bool masked = (*flag) ? (((const unsigned char*)mraw)[b * MX + j] != 0)
                          : (((const int*)mraw)[b * MX + j] != 0);
    v = masked ? 0.0f : 1.0f;
  }
  mm[idx] = v;
}

// ---------------- GEMM: 256x256 tile, BK=64, m201-faithful 8-phase pipeline --
// 512 threads = 8 waves (2 M-waves x 4 N-waves), per-wave output 128x64.
// LDS 128 KiB: per double-buffer d: A[256][64] then B[256][64] (32 KiB each).
// Iteration = 2 K-tiles (ta=2it -> buf0, tb=2it+1 -> buf1), 8 phases; each
// phase: {ds_read afrag (4 b128) [+ bfrag 8 b128 at q==0]; stage one 128-row
// half-tile (2 x global_load_lds); [vmcnt at ph4/ph8]; barrier; setprio(1);
// 16 MFMA; setprio(0); barrier}.
// Stage slots (targets tiles ta2=ta+2 -> buf0, tb2=tb+2 -> buf1):
//   ph1: A-buf1 h0+h1 (tile tb)   [legal: A-buf1 fully read by prev ph8]
//   ph2: B-buf0 h0 (ta2)          [B-buf0 read only at ph1]
//   ph3: B-buf0 h1 (ta2)
//   ph4: -- ; vmcnt(4): lands tb's B (prev ph7/8) + tb's A (ph1);
//             leaves ph2/ph3 in flight
//   ph5: A-buf0 h0 (ta2)          [A-buf0 fully read by ph4]
//   ph6: A-buf0 h1 (ta2)
//   ph7: B-buf1 h0 (tb2)          [B-buf1 read only at ph5]
//   ph8: B-buf1 h1 (tb2); vmcnt(4): lands all of ta2; leaves ph7/8 in flight
// In-order vmcnt ledger verified; never drains to 0 in steady state.
// omode 0: Krows rows; omode 1: V^T (operands swapped); omode 2: Qrows rows.
__global__ __launch_bounds__(512, 2) void gemm256(
    const bf16* __restrict__ A, const bf16* __restrict__ Bt,
    const bf16* __restrict__ Aq, const bf16* __restrict__ Bq,
    bf16* __restrict__ outR, bf16* __restrict__ outVT, bf16* __restrict__ outQ)
{
  __shared__ bf16 sm[65536];                 // 128 KiB: [d][A 16384 | B 16384]

  const int tid = threadIdx.x;
  const int lane = tid & 63, wid = tid >> 6;
  const int wr = wid >> 2, wc = wid & 3;     // 2 x 4 wave grid
  const int lc = lane & 15, lq = lane >> 4;
  const int srow = tid >> 3, sc = tid & 7;
  const int ssw = SWZ(srow, sc) * 8;

  // XCD-bijective swizzle (1120 % 8 == 0): contiguous tile chunk per XCD.
  int bid = blockIdx.x;
  bid = (bid & 7) * 140 + (bid >> 3);

  const bf16 *Arow, *Brow;
  int m0, n0, omode;
  if (bid < 1088) {
    const int by = bid >> 3, bx = bid & 7;
    m0 = by * 256;
    if (bx < 4) { n0 = bx * 256;
      Arow = A  + (size_t)m0 * GK; Brow = Bt + (size_t)n0 * GK; omode = 0; }
    else        { n0 = 1024 + (bx - 4) * 256;
      Arow = Bt + (size_t)n0 * GK; Brow = A  + (size_t)m0 * GK; omode = 1; }
  } else {
    const int ix = bid - 1088;
    m0 = (ix >> 2) * 256; n0 = (ix & 3) * 256;
    Arow = Aq + (size_t)m0 * GK; Brow = Bq + (size_t)n0 * GK; omode = 2;
  }

  const bf16* Abase = Arow + (size_t)srow * GK + ssw;
  const bf16* Bbase = Brow + (size_t)srow * GK + ssw;

  // stage one 128-row half-tile (2 x global_load_lds per thread)
  auto stA = [&](int d, int h, int kt) {
#pragma unroll
    for (int l = 0; l < 2; ++l)
      gl_lds16(Abase + (size_t)(h*128 + l*64) * GK + kt * 64,
               &sm[d*32768 + (h*128 + l*64)*64 + tid*8]);
  };
  auto stB = [&](int d, int h, int kt) {
#pragma unroll
    for (int l = 0; l < 2; ++l)
      gl_lds16(Bbase + (size_t)(h*128 + l*64) * GK + kt * 64,
               &sm[d*32768 + 16384 + (h*128 + l*64)*64 + tid*8]);
  };

  f32x4 acc[8][4];
#pragma unroll
  for (int i = 0; i < 8; i++)
#pragma unroll
    for (int j = 0; j < 4; j++)
#pragma unroll
      for (int r = 0; r < 4; r++) acc[i][j][r] = 0.f;

#define DS_PHASE(d, q, STAGE_STMT, WAIT_STMT)                                  \
  {                                                                            \
    const bf16* As_ = sm + (d)*32768;                                          \
    const bf16* Bs_ = sm + (d)*32768 + 16384;                                  \
    bf16x8 af[2][2];                                                           \
    _Pragma("unroll") for (int mi = 0; mi < 2; ++mi)                           \
      _Pragma("unroll") for (int kk = 0; kk < 2; ++kk)                         \
        af[mi][kk] = *(const bf16x8*)&As_[(wr*128 + ((q)*2+mi)*16 + lc)*64 +   \
                                          SWZ(lc, kk*4 + lq)*8];               \
    if ((q) == 0) {                                                            \
      _Pragma("unroll") for (int n = 0; n < 4; ++n)                            \
        _Pragma("unroll") for (int kk = 0; kk < 2; ++kk)                       \
          bfrag[n][kk] = *(const bf16x8*)&Bs_[(wc*64 + n*16 + lc)*64 +         \
                                              SWZ(lc, kk*4 + lq)*8];           \
    }                                                                          \
    STAGE_STMT;                                                                \
    WAIT_STMT;                                                                 \
    __builtin_amdgcn_s_barrier();                                              \
    __builtin_amdgcn_s_setprio(1);                                             \
    _Pragma("unroll") for (int kk = 0; kk < 2; ++kk)                           \
      _Pragma("unroll") for (int mi = 0; mi < 2; ++mi)                         \
        _Pragma("unroll") for (int n = 0; n < 4; ++n)                          \
          acc[(q)*2+mi][n] = __builtin_amdgcn_mfma_f32_16x16x32_bf16(          \
              af[mi][kk], bfrag[n][kk], acc[(q)*2+mi][n], 0, 0, 0);            \
    __builtin_amdgcn_s_setprio(0);                                             \
    __builtin_amdgcn_s_barrier();                                              \
  }

  // Prologue: tile0 B+A, tile1 B; wait leaves tile1's B (4 loads) in flight.
  stB(0, 0, 0); stB(0, 1, 0);
  stA(0, 0, 0); stA(0, 1, 0);
  stB(1, 0, 1); stB(1, 1, 1);
  VMW(4);
  __builtin_amdgcn_s_barrier();

  bf16x8 bfrag[4][2];
#pragma unroll 1
  for (int it = 0; it < 8; ++it) {
    const int tb = 2*it + 1, ta2 = 2*it + 2, tb2 = 2*it + 3;
    const bool s2 = (ta2 < 16), s3 = (tb2 < 16);
    DS_PHASE(0, 0, { stA(1, 0, tb); stA(1, 1, tb); }, {});
    DS_PHASE(0, 1, { if (s2) stB(0, 0, ta2); }, {});
    DS_PHASE(0, 2, { if (s2) stB(0, 1, ta2); }, {});
    DS_PHASE(0, 3, {}, { if (s2) { VMW(4); } else { VMW(0); } });
    DS_PHASE(1, 0, { if (s2) stA(0, 0, ta2); }, {});
    DS_PHASE(1, 1, { if (s2) stA(0, 1, ta2); }, {});
    DS_PHASE(1, 2, { if (s3) stB(1, 0, tb2); }, {});
    DS_PHASE(1, 3, { if (s3) stB(1, 1, tb2); }, { if (s3) { VMW(4); } });
  }
#undef DS_PHASE

  // ---- Epilogue: acc -> bf16 Ct[256][256] in LDS (32-chunk swizzle), then
  //      coalesced 16B row-major stores.
  __syncthreads();
  bf16* Ct = sm;
#pragma unroll
  for (int m = 0; m < 8; ++m)
#pragma unroll
    for (int n = 0; n < 4; ++n) {
      const int col = wc*64 + n*16 + lc;
      const int cch = col >> 3, cw = col & 7;
#pragma unroll
      for (int r = 0; r < 4; ++r) {
        const int row = wr*128 + m*16 + lq*4 + r;
        Ct[row*256 + (((cch ^ (row & 31)) << 3) + cw)] = (bf16)acc[m][n][r];
      }
    }
  __syncthreads();

  const int cch = tid & 31, r0 = tid >> 5;
  if (omode != 1) {
    bf16* dst0 = (omode == 0 ? outR : outQ);
#pragma unroll
    for (int i = 0; i < 16; ++i) {
      const int row = r0 + i*16;
      bf16x8 v = *(const bf16x8*)&Ct[row*256 + ((cch ^ (row & 31)) << 3)];
      *(bf16x8*)(dst0 + (size_t)(m0 + row) * 1024 + n0 + cch*8) = v;
    }
  } else {
    const int bb = m0 / JD;                // 256-row m-tiles never cross batches (JD = 17*256)
    const int jbase = m0 - bb * JD;
#pragma unroll
    for (int i = 0; i < 16; ++i) {
      const int row = r0 + i*16;
      const int cc = n0 + row - 1024;      // weight col in V half
      bf16x8 v = *(const bf16x8*)&Ct[row*256 + ((cch ^ (row & 31)) << 3)];
      bf16* dst = outVT + (((size_t)(bb*HEADS + (cc >> 6)))*64 + (cc & 63)) * JD
                        + jbase + cch*8;
      *(bf16x8*)dst = v;
    }
  }
}

// ---------------- GEMM: 128x128 tile, BK=64 (final projection, f32 out) -----
__global__ __launch_bounds__(256) void gemm128(
    const bf16* __restrict__ A, const bf16* __restrict__ Bt,
    float* __restrict__ Cf, int N)
{
  __shared__ bf16 smem[2 * 128 * 64];
  bf16* As = smem;
  bf16* Bs = smem + 128 * 64;

  const int tid = threadIdx.x;
  const int lane = tid & 63, wid = tid >> 6;
  const int wr = wid >> 1, wc = wid & 1;
  const int m0 = blockIdx.y * 128;
  const int n0 = blockIdx.x * 128;
  const int srow = tid >> 3, sc = tid & 7;
  const int ssw = SWZ(srow, sc) * 8;     // swizzled source chunk (elements)
  const int lc = lane & 15, lq = lane >> 4;

  f32x4 acc[4][4];
#pragma unroll
  for (int i = 0; i < 4; i++)
#pragma unroll
    for (int j = 0; j < 4; j++)
#pragma unroll
      for (int r = 0; r < 4; r++) acc[i][j][r] = 0.f;

  const bf16* Abase = A + (size_t)m0 * GK + (size_t)srow * GK + ssw;
  const bf16* Bbase = Bt + (size_t)n0 * GK + (size_t)srow * GK + ssw;

  for (int k0 = 0; k0 < GK; k0 += 64) {
    __syncthreads();
#pragma unroll
    for (int q = 0; q < 4; q++) {
      gl_lds16(Abase + (size_t)q * 32 * GK + k0, &As[(srow + q*32) * 64 + sc*8]);
      gl_lds16(Bbase + (size_t)q * 32 * GK + k0, &Bs[(srow + q*32) * 64 + sc*8]);
    }
    VMW(0);
    __syncthreads();
#pragma unroll
    for (int kk = 0; kk < 2; kk++) {
      bf16x8 af[4], bfr[4];
#pragma unroll
      for (int mi = 0; mi < 4; mi++)
        af[mi] = *(const bf16x8*)&As[(wr*64 + mi*16 + lc) * 64 + SWZ(lc, kk*4 + lq)*8];
#pragma unroll
      for (int ni = 0; ni < 4; ni++)
        bfr[ni] = *(const bf16x8*)&Bs[(wc*64 + ni*16 + lc) * 64 + SWZ(lc, kk*4 + lq)*8];
#pragma unroll
      for (int mi = 0; mi < 4; mi++)
#pragma unroll
        for (int ni = 0; ni < 4; ni++)
          acc[mi][ni] = __builtin_amdgcn_mfma_f32_16x16x32_bf16(af[mi], bfr[ni], acc[mi][ni], 0, 0, 0);
    }
  }

#pragma unroll
  for (int mi = 0; mi < 4; mi++)
#pragma unroll
    for (int ni = 0; ni < 4; ni++) {
      const int r = m0 + wr*64 + mi*16 + lq*4;
      const int c = n0 + wc*64 + ni*16 + lc;
#pragma unroll
      for (int reg = 0; reg < 4; reg++)
        Cf[(size_t)(r + reg) * N + c] = acc[mi][ni][reg];
    }
}

// ---------------- Attention --------------------------------------------------
// 256 blocks = (b,h) x 2 q-tiles of 128; 512 threads (8 waves, 16 q-rows each).
// K/V double-buffered in LDS with counted vmcnt(2): tile t+2 staged after the
// compute barrier; wait covers tile t+1 (issued a full iteration earlier).
__global__ __launch_bounds__(512) void attn_kernel(
    const bf16* __restrict__ Qrows,  // [2048][1024]
    const bf16* __restrict__ Krows,  // [B*JD][1024]
    const bf16* __restrict__ VT,     // [B][H][64][JD]
    const float* __restrict__ mmul,  // [B][JD]
    bf16* __restrict__ outp)         // [2048][1024]
{
  const int bh = blockIdx.x >> 1, qt = blockIdx.x & 1;
  const int b = bh >> 4, h = bh & 15;
  __shared__ bf16 Qs[128 * 64];
  __shared__ bf16 Ks[2][64 * 64];
  __shared__ bf16 VTs[2][64 * 64];
  __shared__ bf16 Ps[8][16 * 64];
  const int tid = threadIdx.x, lane = tid & 63, w = tid >> 6;
  const int lc = lane & 15, lq = lane >> 4;
  const int srow = tid >> 3, sc = tid & 7;
  const int ssw = SWZ(srow, sc) * 8;

  const bf16* Qg = Qrows + ((size_t)(b*MQ + qt*128)) * 1024 + h*64;
  const bf16* Kg = Krows + ((size_t)b * JD) * 1024 + h*64;
  const bf16* Vg = VT + ((size_t)bh * 64) * JD;

  auto stKV = [&](int c, int t) {
    gl_lds16(Kg + (size_t)(t*64 + srow) * 1024 + ssw, &Ks[c][tid*8]);
    gl_lds16(Vg + (size_t)srow * JD + t*64 + ssw, &VTs[c][tid*8]);
  };

  gl_lds16(Qg + (size_t)srow * 1024 + ssw, &Qs[tid*8]);
  gl_lds16(Qg + (size_t)(srow + 64) * 1024 + ssw, &Qs[(tid + 512)*8]);
  stKV(0, 0);
  stKV(1, 1);
  VMW(2);                                   // Q + tile0 landed; tile1 in flight
  __syncthreads();

  bf16x8 qf[2];
#pragma unroll
  for (int kk = 0; kk < 2; kk++)
    qf[kk] = *(const bf16x8*)&Qs[(w*16 + lc) * 64 + SWZ(lc, kk*4 + lq)*8];

  f32x4 oacc[4];
  float den[4];
#pragma unroll
  for (int di = 0; di < 4; di++)
#pragma unroll
    for (int r = 0; r < 4; r++) oacc[di][r] = 0.f;
#pragma unroll
  for (int r = 0; r < 4; r++) den[r] = 0.f;

#pragma unroll 1
  for (int t = 0; t < JD/64; ++t) {
    const int c = t & 1;
    const int j0 = t * 64;

    // S = Q K^T
    f32x4 sacc[4];
#pragma unroll
    for (int nj = 0; nj < 4; nj++)
#pragma unroll
      for (int r = 0; r < 4; r++) sacc[nj][r] = 0.f;
#pragma unroll
    for (int kk = 0; kk < 2; kk++) {
      bf16x8 kf[4];
#pragma unroll
      for (int nj = 0; nj < 4; nj++)
        kf[nj] = *(const bf16x8*)&Ks[c][(nj*16 + lc) * 64 + SWZ(lc, kk*4 + lq)*8];
#pragma unroll
      for (int nj = 0; nj < 4; nj++)
        sacc[nj] = __builtin_amdgcn_mfma_f32_16x16x32_bf16(qf[kk], kf[nj], sacc[nj], 0, 0, 0);
    }

    // P = exp(S*scale) * mask ; partial denominators ; stage P for PV
#pragma unroll
    for (int nj = 0; nj < 4; nj++) {
      const float mm = mmul[b * JD + j0 + nj*16 + lc];
#pragma unroll
      for (int r = 0; r < 4; r++) {
        // scale * log2(e) = 0.125 * 1.4426950 = 0.18033688
        const float p = exp2f(sacc[nj][r] * 0.18033688f) * mm;
        den[r] += p;
        const int row = lq*4 + r, col = nj*16 + lc;
        Ps[w][row*64 + (((col >> 3) ^ (row & 7)) << 3) + (col & 7)] = (bf16)p;
      }
    }

    // O += P V
#pragma unroll
    for (int kk = 0; kk < 2; kk++) {
      bf16x8 pf = *(const bf16x8*)&Ps[w][lc*64 + SWZ(lc, kk*4 + lq)*8];
#pragma unroll
      for (int di = 0; di < 4; di++) {
        bf16x8 vf = *(const bf16x8*)&VTs[c][(di*16 + lc) * 64 + SWZ(lc, kk*4 + lq)*8];
        oacc[di] = __builtin_amdgcn_mfma_f32_16x16x32_bf16(pf, vf, oacc[di], 0, 0, 0);
      }
    }

    __builtin_amdgcn_s_barrier();           // all waves done with buf c
    if (t + 2 < JD/64) {
      stKV(c, t + 2);
      VMW(2);                               // tile t+1 landed; t+2 in flight
    } else if (t + 1 < JD/64) {
      VMW(0);                               // drain last prefetch
    }
    __builtin_amdgcn_s_barrier();
  }

#pragma unroll
  for (int r = 0; r < 4; r++) {
    float d = den[r];
    d += __shfl_xor(d, 1); d += __shfl_xor(d, 2);
    d += __shfl_xor(d, 4); d += __shfl_xor(d, 8);
    den[r] = 1.0f / d;
  }

#pragma unroll
  for (int di = 0; di < 4; di++) {
    const int col = h*64 + di*16 + lc;
#pragma unroll
    for (int r = 0; r < 4; r++) {
      const int i = qt*128 + w*16 + lq*4 + r;
      outp[(size_t)(b*MQ + i) * 1024 + col] = (bf16)(oacc[di][r] * den[r]);
    }
  }
}

// ---------------- launch -----------------------------------------------------
extern "C" void kernel_launch(void* const* d_in, const int* in_sizes, int n_in,
                              void* d_out, int out_size, void* d_ws, size_t ws_size,
                              hipStream_t stream)
{
  const float* x    = (const float*)d_in[0];
  const float* lat  = (const float*)d_in[1];
  const void*  mraw = d_in[2];
  const float* nm_g = (const float*)d_in[3];
  const float* nm_b = (const float*)d_in[4];
  const float* nl_g = (const float*)d_in[5];
  const float* nl_b = (const float*)d_in[6];
  const float* Wq   = (const float*)d_in[7];
  const float* Wkv  = (const float*)d_in[8];
  const float* Wo   = (const float*)d_in[9];
  float* out = (float*)d_out;

  char* p = (char*)d_ws;
  auto alloc = [&](size_t bytes) { char* r = p; p += (bytes + 255) & ~(size_t)255; return r; };

  bf16*  kv_in  = (bf16*)alloc((size_t)NB * JD * DIMV * 2);          // 71.3 MB
  bf16*  Krows  = (bf16*)alloc((size_t)NB * JD * 1024 * 2);          // 71.3 MB
  bf16*  VTbuf  = (bf16*)alloc((size_t)NB * HEADS * 64 * JD * 2);    // 71.3 MB
  bf16*  WqT    = (bf16*)alloc((size_t)1024 * 1024 * 2);
  bf16*  WkvT   = (bf16*)alloc((size_t)2048 * 1024 * 2);
  bf16*  WoT    = (bf16*)alloc((size_t)1024 * 1024 * 2);
  bf16*  ln_buf = (bf16*)alloc((size_t)NB * MQ * DIMV * 2);
  bf16*  Qrows  = (bf16*)alloc((size_t)NB * MQ * 1024 * 2);
  bf16*  attout = (bf16*)alloc((size_t)NB * MQ * DIMV * 2);
  float* mmulp  = (float*)alloc((size_t)NB * JD * 4);
  int*   flag   = (int*)alloc(256);
  (void)ws_size; (void)in_sizes; (void)n_in; (void)out_size;

  ln_kernel<<<NB * MX, 256, 0, stream>>>(x,   nm_g, nm_b, kv_in, nullptr, 0);
  ln_kernel<<<NB * MQ, 256, 0, stream>>>(lat, nl_g, nl_b, kv_in, ln_buf, 1);
  transpose_w<<<256, 256, 0, stream>>>(Wq,  WqT,  1024, 1024);
  transpose_w<<<512, 256, 0, stream>>>(Wkv, WkvT, 1024, 2048);
  transpose_w<<<256, 256, 0, stream>>>(Wo,  WoT,  1024, 1024);
  mask_detect<<<1, 256, 0, stream>>>((const unsigned char*)mraw, 32768, flag);
  mask_build<<<136, 256, 0, stream>>>(mraw, flag, mmulp);

  // kv = kv_in @ Wkv (K rows + V^T) AND q = ln @ Wq, all as 256^2 tiles:
  // 1088 KV tiles + 32 Q tiles = 1120 blocks (%8==0 for XCD swizzle).
  gemm256<<<1120, 512, 0, stream>>>(kv_in, WkvT, ln_buf, WqT, Krows, VTbuf, Qrows);
  attn_kernel<<<256, 512, 0, stream>>>(Qrows, Krows, VTbuf, mmulp, attout);
  // out = attout @ Wo -> f32 d_out
  gemm128<<<dim3(8, 16), 256, 0, stream>>>(attout, WoT, out, 1024);
}